// Round 4
// baseline (18215.590 us; speedup 1.0000x reference)
//
#include <hip/hip_runtime.h>
#include <math.h>

#define NB 512      // batch
#define NT 512      // time
#define NCTRL 256
#define NWORD 128
#define NMEM 128
#define NDIN 64
#define NACT 448    // x(64) | read(128) | ctrl(256)
#define EPSF 1e-6f

// fp32 workspace layout (element offsets) — fast path only
#define OFF_WA   0        // [448][512]  fused r,z weights (transposed)
#define OFF_WNI  229376   // [192][256]  W_ih rows 512..767 transposed (inn)
#define OFF_WNH  278528   // [256][256]  W_hh rows 512..767 transposed (hn)
#define OFF_WH   344064   // [256][512]  heads: key|erase|add|beta|pad (transposed)
#define OFF_BA   475136   // [512]  b_ih[j]+b_hh[j]
#define OFF_BNI  475648   // [256]  b_ih[512+i]
#define OFF_BNH  475904   // [256]  b_hh[512+i]
#define OFF_BH   476160   // [512]  [b_key|b_erase|b_add|b_beta|0]
#define WS_FLOATS 476672

__device__ __forceinline__ float sigf(float x) { return 1.0f / (1.0f + expf(-x)); }
__device__ __forceinline__ float softplusf(float x) {
    return (x > 15.0f) ? x : log1pf(expf(x));
}

__global__ __launch_bounds__(256) void prep_kernel(
    const float* __restrict__ Wih, const float* __restrict__ bih,
    const float* __restrict__ Whh, const float* __restrict__ bhh,
    const float* __restrict__ Wkey, const float* __restrict__ bkey,
    const float* __restrict__ Wbeta, const float* __restrict__ bbeta,
    const float* __restrict__ Wer, const float* __restrict__ ber,
    const float* __restrict__ Wadd, const float* __restrict__ badd,
    float* __restrict__ ws)
{
    int i = blockIdx.x * 256 + threadIdx.x;
    if (i >= WS_FLOATS) return;
    float v;
    if (i < OFF_WNI) {                       // WA_T [448][512]
        int k = i >> 9, j = i & 511;
        v = (k < 192) ? Wih[j * 192 + k] : Whh[j * 256 + (k - 192)];
    } else if (i < OFF_WNH) {                // WNI_T [192][256]
        int i2 = i - OFF_WNI; int k = i2 >> 8, c = i2 & 255;
        v = Wih[(512 + c) * 192 + k];
    } else if (i < OFF_WH) {                 // WNH_T [256][256]
        int i2 = i - OFF_WNH; int k = i2 >> 8, c = i2 & 255;
        v = Whh[(512 + c) * 256 + k];
    } else if (i < OFF_BA) {                 // WH_T [256][512]
        int i2 = i - OFF_WH; int k = i2 >> 9, c = i2 & 511;
        if (c < 128)       v = Wkey[c * 256 + k];
        else if (c < 256)  v = Wer[(c - 128) * 256 + k];
        else if (c < 384)  v = Wadd[(c - 256) * 256 + k];
        else if (c == 384) v = Wbeta[k];
        else               v = 0.0f;
    } else if (i < OFF_BNI) {
        int j = i - OFF_BA;
        v = bih[j] + bhh[j];
    } else if (i < OFF_BNH) {
        v = bih[512 + (i - OFF_BNI)];
    } else if (i < OFF_BH) {
        v = bhh[512 + (i - OFF_BNH)];
    } else {
        int c = i - OFF_BH;
        if (c < 128)       v = bkey[c];
        else if (c < 256)  v = ber[c - 128];
        else if (c < 384)  v = badd[c - 256];
        else if (c == 384) v = bbeta[0];
        else               v = 0.0f;
    }
    ws[i] = v;
}

// Shared memory module: needs keyv/ev/av/scal[1] ready and a sync before entry.
// Reads OLD M for cos+read, then erase/add-updates M in place. Ends synced.
__device__ __forceinline__ void memory_step(
    int tid, float (*M)[NWORD + 1],
    const float* keyv, const float* ev, const float* av,
    float* cosb, float* wb, float* part, float* readv, float* scal)
{
    if (tid < 64) {                       // ||k||
        float s = keyv[tid] * keyv[tid] + keyv[tid + 64] * keyv[tid + 64];
        #pragma unroll
        for (int o = 32; o >= 1; o >>= 1) s += __shfl_xor(s, o);
        if (tid == 0) scal[0] = 1.0f / (sqrtf(s) + EPSF);
    }
    __syncthreads();
    {                                      // cosine sim: 2 threads / row
        int rr = tid >> 1, hh = tid & 1;
        const float* Mr = &M[rr][hh * 64];
        const float* kk = keyv + hh * 64;
        float s2 = 0.f, sc = 0.f;
        #pragma unroll 8
        for (int j = 0; j < 64; ++j) { float m = Mr[j]; s2 = fmaf(m, m, s2); sc = fmaf(m, kk[j], sc); }
        s2 += __shfl_xor(s2, 1);
        sc += __shfl_xor(sc, 1);
        if (hh == 0) cosb[rr] = sc * scal[0] / (sqrtf(s2) + EPSF);
    }
    __syncthreads();
    if (tid < 64) {                       // softmax over 128 logits
        float beta = scal[1];
        float l0 = beta * cosb[tid], l1 = beta * cosb[tid + 64];
        float mx = fmaxf(l0, l1);
        #pragma unroll
        for (int o = 32; o >= 1; o >>= 1) mx = fmaxf(mx, __shfl_xor(mx, o));
        float e0 = expf(l0 - mx), e1 = expf(l1 - mx);
        float s = e0 + e1;
        #pragma unroll
        for (int o = 32; o >= 1; o >>= 1) s += __shfl_xor(s, o);
        float inv = 1.0f / s;
        wb[tid] = e0 * inv;
        wb[tid + 64] = e1 * inv;
    }
    __syncthreads();
    {                                      // read = w . OLD M  (col-wise)
        int j = tid & 127, hf = tid >> 7;
        float p = 0.f;
        #pragma unroll 8
        for (int r = 0; r < 64; ++r) p = fmaf(wb[hf * 64 + r], M[hf * 64 + r][j], p);
        part[hf * 128 + j] = p;
    }
    __syncthreads();
    if (tid < 128) readv[tid] = part[tid] + part[128 + tid];
    {                                      // M = M - w*(e*M - a)
        int rr = tid >> 1, hh = tid & 1;
        float wr = wb[rr];
        #pragma unroll 8
        for (int i = 0; i < 64; ++i) {
            int j = hh * 64 + i;
            float m = M[rr][j];
            M[rr][j] = fmaf(-wr, fmaf(ev[j], m, -av[j]), m);
        }
    }
    __syncthreads();
}

// FAST path: transposed fp32 weight panels in ws. 1 WG / row; M in LDS.
__global__ __launch_bounds__(256) void ntm_fast(
    const float* __restrict__ data, const int* __restrict__ batch_sizes,
    const int* __restrict__ unsort, const float* __restrict__ M0,
    const float* __restrict__ ws, float* __restrict__ out)
{
    __shared__ float M[NMEM][NWORD + 1];
    __shared__ float actA[NACT];
    __shared__ float ctrlB[NCTRL];
    __shared__ float readv[NWORD], keyv[NWORD], ev[NWORD], av[NWORD];
    __shared__ float cosb[NMEM], wb[NMEM], part[2 * NWORD], scal[2];
    __shared__ int len_sh;

    const int tid = threadIdx.x;
    const int g = blockIdx.x;
    const int b = unsort[g];

    if (tid == 0) {
        int L = 0;
        for (int t = 0; t < NT; ++t) L += (batch_sizes[t] > b);
        len_sh = L;
    }
    for (int i = tid; i < NMEM * NWORD; i += 256)
        M[i >> 7][i & 127] = M0[i];
    ctrlB[tid] = 0.0f;
    if (tid < NWORD) readv[tid] = 0.0f;
    __syncthreads();
    const int len = len_sh;   // batch_sizes non-increasing -> active steps are a prefix

    const float bA0 = ws[OFF_BA + tid],  bA1 = ws[OFF_BA + 256 + tid];
    const float bNi = ws[OFF_BNI + tid], bNh = ws[OFF_BNH + tid];
    const float bH0 = ws[OFF_BH + tid],  bH1 = ws[OFF_BH + 256 + tid];

    for (int t = 0; t < len; ++t) {
        if (tid < 64)  actA[tid] = data[((long)t * NB + b) * NDIN + tid];
        if (tid < 128) actA[64 + tid] = readv[tid];
        actA[192 + tid] = ctrlB[tid];       // old ctrl copy
        __syncthreads();

        float a0 = bA0, a1 = bA1;           // r (col tid), z (col tid+256)
        {
            const float* wa = ws + OFF_WA + tid;
            #pragma unroll 8
            for (int k = 0; k < 448; ++k) {
                float v = actA[k];
                a0 = fmaf(v, wa[0], a0);
                a1 = fmaf(v, wa[256], a1);
                wa += 512;
            }
        }
        float ai = bNi, ah = bNh;           // inn, hn
        {
            const float* w = ws + OFF_WNI + tid;
            #pragma unroll 8
            for (int k = 0; k < 192; ++k) { ai = fmaf(actA[k], w[0], ai); w += 256; }
        }
        {
            const float* w = ws + OFF_WNH + tid;
            #pragma unroll 8
            for (int k = 0; k < 256; ++k) { ah = fmaf(actA[192 + k], w[0], ah); w += 256; }
        }
        float rg = sigf(a0), zg = sigf(a1);
        float ng = tanhf(fmaf(rg, ah, ai));
        float cold = actA[192 + tid];
        ctrlB[tid] = fmaf(zg, cold - ng, ng);
        __syncthreads();

        float h0 = bH0, h1 = bH1;           // head cols tid, tid+256
        {
            const float* wh = ws + OFF_WH + tid;
            #pragma unroll 8
            for (int k = 0; k < 256; ++k) {
                float v = ctrlB[k];
                h0 = fmaf(v, wh[0], h0);
                h1 = fmaf(v, wh[256], h1);
                wh += 512;
            }
        }
        if (tid < 128) { keyv[tid] = tanhf(h0); av[tid] = h1; }
        else           { ev[tid - 128] = sigf(h0); }
        if (tid == 128) scal[1] = softplusf(h1);   // col 384 = beta
        __syncthreads();

        memory_step(tid, M, keyv, ev, av, cosb, wb, part, readv, scal);
    }

    out[g * NCTRL + tid] = ctrlB[tid];
    if (tid < NWORD) out[NB * NCTRL + g * NWORD + tid] = readv[tid];
}

// FALLBACK (ws too small): native-layout weights, wave-per-output GEMVs.
__global__ __launch_bounds__(256) void ntm_slow(
    const float* __restrict__ data, const int* __restrict__ batch_sizes,
    const int* __restrict__ unsort,
    const float* __restrict__ Wih, const float* __restrict__ bih,
    const float* __restrict__ Whh, const float* __restrict__ bhh,
    const float* __restrict__ Wkey, const float* __restrict__ bkey,
    const float* __restrict__ Wbeta, const float* __restrict__ bbeta,
    const float* __restrict__ Wer, const float* __restrict__ ber,
    const float* __restrict__ Wadd, const float* __restrict__ badd,
    const float* __restrict__ M0, float* __restrict__ out)
{
    __shared__ float M[NMEM][NWORD + 1];
    __shared__ float act[NACT];
    __shared__ float ctrlB[NCTRL];
    __shared__ float gpre[512], ginn[256], ghn[256], hpre[448];
    __shared__ float readv[NWORD], keyv[NWORD], ev[NWORD], av[NWORD];
    __shared__ float cosb[NMEM], wb[NMEM], part[2 * NWORD], scal[2];
    __shared__ int len_sh;

    const int tid = threadIdx.x;
    const int g = blockIdx.x;
    const int b = unsort[g];

    if (tid == 0) {
        int L = 0;
        for (int t = 0; t < NT; ++t) L += (batch_sizes[t] > b);
        len_sh = L;
    }
    for (int i = tid; i < NMEM * NWORD; i += 256)
        M[i >> 7][i & 127] = M0[i];
    ctrlB[tid] = 0.0f;
    if (tid < NWORD) readv[tid] = 0.0f;
    __syncthreads();
    const int len = len_sh;

    const int wave = tid >> 6, lane = tid & 63;

    for (int t = 0; t < len; ++t) {
        if (tid < 64)  act[tid] = data[((long)t * NB + b) * NDIN + tid];
        if (tid < 128) act[64 + tid] = readv[tid];
        act[192 + tid] = ctrlB[tid];
        __syncthreads();

        for (int j = wave; j < 512; j += 4) {          // fused r,z pre-acts
            float p = 0.f;
            for (int k = lane; k < 192; k += 64) p = fmaf(act[k], Wih[j * 192 + k], p);
            for (int k = lane; k < 256; k += 64) p = fmaf(act[192 + k], Whh[j * 256 + k], p);
            #pragma unroll
            for (int o = 32; o >= 1; o >>= 1) p += __shfl_xor(p, o);
            if (lane == 0) gpre[j] = p;
        }
        for (int j = wave; j < 256; j += 4) {          // inn, hn
            float pi = 0.f, ph = 0.f;
            for (int k = lane; k < 192; k += 64) pi = fmaf(act[k], Wih[(512 + j) * 192 + k], pi);
            for (int k = lane; k < 256; k += 64) ph = fmaf(act[192 + k], Whh[(512 + j) * 256 + k], ph);
            #pragma unroll
            for (int o = 32; o >= 1; o >>= 1) { pi += __shfl_xor(pi, o); ph += __shfl_xor(ph, o); }
            if (lane == 0) { ginn[j] = pi; ghn[j] = ph; }
        }
        __syncthreads();

        {
            float r = sigf(gpre[tid] + bih[tid] + bhh[tid]);
            float z = sigf(gpre[256 + tid] + bih[256 + tid] + bhh[256 + tid]);
            float inn = ginn[tid] + bih[512 + tid];
            float hn  = ghn[tid] + bhh[512 + tid];
            float n = tanhf(fmaf(r, hn, inn));
            float cold = act[192 + tid];
            ctrlB[tid] = fmaf(z, cold - n, n);
        }
        __syncthreads();

        for (int j = wave; j < 385; j += 4) {          // heads
            const float* Wp; long base;
            if (j < 128)      { Wp = Wkey;  base = (long)j * 256; }
            else if (j < 256) { Wp = Wer;   base = (long)(j - 128) * 256; }
            else if (j < 384) { Wp = Wadd;  base = (long)(j - 256) * 256; }
            else              { Wp = Wbeta; base = 0; }
            float p = 0.f;
            for (int k = lane; k < 256; k += 64) p = fmaf(ctrlB[k], Wp[base + k], p);
            #pragma unroll
            for (int o = 32; o >= 1; o >>= 1) p += __shfl_xor(p, o);
            if (lane == 0) hpre[j] = p;
        }
        __syncthreads();
        if (tid < 128) {
            keyv[tid] = tanhf(hpre[tid] + bkey[tid]);
            ev[tid]   = sigf(hpre[128 + tid] + ber[tid]);
            av[tid]   = hpre[256 + tid] + badd[tid];
        }
        if (tid == 0) scal[1] = softplusf(hpre[384] + bbeta[0]);
        __syncthreads();

        memory_step(tid, M, keyv, ev, av, cosb, wb, part, readv, scal);
    }

    out[g * NCTRL + tid] = ctrlB[tid];
    if (tid < NWORD) out[NB * NCTRL + g * NWORD + tid] = readv[tid];
}

extern "C" void kernel_launch(void* const* d_in, const int* in_sizes, int n_in,
                              void* d_out, int out_size, void* d_ws, size_t ws_size,
                              hipStream_t stream)
{
    const float* data       = (const float*)d_in[0];
    const int*  batch_sizes = (const int*)d_in[1];
    const int*  unsort      = (const int*)d_in[2];
    float* out = (float*)d_out;

    if (ws_size >= (size_t)WS_FLOATS * sizeof(float)) {
        float* ws = (float*)d_ws;
        prep_kernel<<<(WS_FLOATS + 255) / 256, 256, 0, stream>>>(
            (const float*)d_in[3], (const float*)d_in[4], (const float*)d_in[5],
            (const float*)d_in[6], (const float*)d_in[7], (const float*)d_in[8],
            (const float*)d_in[9], (const float*)d_in[10], (const float*)d_in[11],
            (const float*)d_in[12], (const float*)d_in[13], (const float*)d_in[14], ws);
        ntm_fast<<<NB, 256, 0, stream>>>(data, batch_sizes, unsort,
                                         (const float*)d_in[15], ws, out);
    } else {
        ntm_slow<<<NB, 256, 0, stream>>>(
            data, batch_sizes, unsort,
            (const float*)d_in[3], (const float*)d_in[4], (const float*)d_in[5],
            (const float*)d_in[6], (const float*)d_in[7], (const float*)d_in[8],
            (const float*)d_in[9], (const float*)d_in[10], (const float*)d_in[11],
            (const float*)d_in[12], (const float*)d_in[13], (const float*)d_in[14],
            (const float*)d_in[15], out);
    }
}